// Round 3
// baseline (535.910 us; speedup 1.0000x reference)
//
#include <hip/hip_runtime.h>

// TAMCaD_T fused attention-over-variables.
// q,k,v: (B=16, G=32, H=32, S=4096) fp32, s contiguous.
// Per (b,s): logits[g][f] = scale * sum_d q[g,d]k[f,d]; attn = softmax_f; x[g,d] = sum_f attn*v[f,d].
// Outputs (concat fp32): x (B,G*H,S) | attentions (B,G,G,S) | logits (B,G,G,S).
//
// Round-3 structure: thread = (g, s) owns the FULL f-row -> softmax is thread-local,
// attn never touches LDS, ONE barrier total. All input loads issued up front.
// k/v staged as bf16 d-pair u32s in LDS layout [f][s][16 slots], chunk-XOR-swizzled
// by (s>>1)&3 so hot-loop ds_read_b128s are conflict-free with immediate offsets only.

constexpr int S_LEN = 4096;
constexpr int GG = 32;   // groups (q and kv)
constexpr int HH = 32;   // hidden dim (dk), n_heads = 1
constexpr int TS = 16;   // timesteps per block -> 64-B global segments
constexpr float SCALE = 0.17677669529663687f;  // 32^-0.5

__device__ __forceinline__ unsigned bf16pack(float a, float b) {
    // round-to-nearest-even bf16 pair in a u32 (lo = a, hi = b)
    unsigned ua = __float_as_uint(a);
    unsigned ub = __float_as_uint(b);
    ua = (ua + 0x7fffu + ((ua >> 16) & 1u)) >> 16;
    ub = (ub + 0x7fffu + ((ub >> 16) & 1u)) >> 16;
    return ua | (ub << 16);
}

__global__ __launch_bounds__(512, 4) void tamcad_fused(
    const float* __restrict__ q, const float* __restrict__ k,
    const float* __restrict__ v, float* __restrict__ x_out,
    float* __restrict__ attn_out, float* __restrict__ logit_out)
{
    // single pool: k tile = lds[0..8192), v tile = lds[8192..16384). 64 KB.
    // u32 index for element (f, d=2*dp+h, s): f*256 + s*16 + slot(dp,s)
    //   slot(dp,s) = (((dp>>2) ^ ((s>>1)&3)) << 2) | (dp&3)
    __shared__ __align__(16) unsigned lds[GG * TS * 16 * 2];

    // XCD-bijective swizzle (nwg = 4096, divisible by 8)
    const int nwg = gridDim.x;
    const int cpx = nwg >> 3;
    const int raw = blockIdx.x;
    const int logical = (raw & 7) * cpx + (raw >> 3);
    const int b  = logical >> 8;       // / (S/TS = 256)
    const int st = logical & 255;
    const int s0 = st * TS;

    const int tid = threadIdx.x;
    const int g = tid >> 4;            // 0..31
    const int s = tid & 15;            // 0..15

    const int baseB = b * (GG * HH);
    const float* qb = q + (size_t)baseB * S_LEN + s0;
    const float* kb = k + (size_t)baseB * S_LEN + s0;
    const float* vb = v + (size_t)baseB * S_LEN + s0;

    // ---- q -> registers (issued first; 32 independent b32 loads) ----
    float qreg[32];
    #pragma unroll
    for (int d = 0; d < 32; ++d)
        qreg[d] = qb[(size_t)(g * HH + d) * S_LEN + s];

    // ---- stage k, v -> LDS (bf16 d-pairs) ----
    {
        const int fst = g;             // staging row-group = tid>>4
        const int dp  = s;             // d-pair 0..15 -> rows 2dp, 2dp+1
        const int dpl = dp & 3;
        const int dph = (dp >> 2) << 2;
        unsigned* const wbase = &lds[fst * 256 + dpl];
        unsigned* const was[4] = { wbase + (dph ^ 0),  wbase + (dph ^ 4),
                                   wbase + (dph ^ 8),  wbase + (dph ^ 12) };

        const float4* k0p = reinterpret_cast<const float4*>(kb + (size_t)(fst * HH + 2 * dp)     * S_LEN);
        const float4* k1p = reinterpret_cast<const float4*>(kb + (size_t)(fst * HH + 2 * dp + 1) * S_LEN);
        const float4* v0p = reinterpret_cast<const float4*>(vb + (size_t)(fst * HH + 2 * dp)     * S_LEN);
        const float4* v1p = reinterpret_cast<const float4*>(vb + (size_t)(fst * HH + 2 * dp + 1) * S_LEN);

        float r0[16], r1[16], t0[16], t1[16];
        #pragma unroll
        for (int sq = 0; sq < 4; ++sq) {
            *reinterpret_cast<float4*>(&r0[sq * 4]) = k0p[sq];
            *reinterpret_cast<float4*>(&r1[sq * 4]) = k1p[sq];
            *reinterpret_cast<float4*>(&t0[sq * 4]) = v0p[sq];
            *reinterpret_cast<float4*>(&t1[sq * 4]) = v1p[sq];
        }
        #pragma unroll
        for (int ss = 0; ss < 16; ++ss) {
            unsigned* wp = was[(ss >> 1) & 3] + ss * 16;
            wp[0]    = bf16pack(r0[ss], r1[ss]);   // k
            wp[8192] = bf16pack(t0[ss], t1[ss]);   // v
        }
    }
    __syncthreads();   // the only barrier

    // ---- hot-loop read pointers: chunk c lives at group (c ^ xs) ----
    const int xs = (s >> 1) & 3;
    const unsigned* const rp0 = &lds[s * 16 + ((0 ^ xs) << 2)];
    const unsigned* const rp1 = &lds[s * 16 + ((1 ^ xs) << 2)];
    const unsigned* const rp2 = &lds[s * 16 + ((2 ^ xs) << 2)];
    const unsigned* const rp3 = &lds[s * 16 + ((3 ^ xs) << 2)];

    // ---- QK^T: l[f] for all 32 f ----
    float l[32];
#define QKW(u, d0) { \
        const float klo_ = __uint_as_float((u) << 16); \
        const float khi_ = __uint_as_float((u) & 0xffff0000u); \
        a0 = fmaf(qreg[d0], klo_, a0); \
        a1 = fmaf(qreg[(d0) + 1], khi_, a1); }
    #pragma unroll
    for (int f = 0; f < 32; ++f) {
        float a0 = 0.f, a1 = 0.f;
        const uint4 c0 = *reinterpret_cast<const uint4*>(rp0 + f * 256);
        const uint4 c1 = *reinterpret_cast<const uint4*>(rp1 + f * 256);
        const uint4 c2 = *reinterpret_cast<const uint4*>(rp2 + f * 256);
        const uint4 c3 = *reinterpret_cast<const uint4*>(rp3 + f * 256);
        QKW(c0.x,  0) QKW(c0.y,  2) QKW(c0.z,  4) QKW(c0.w,  6)
        QKW(c1.x,  8) QKW(c1.y, 10) QKW(c1.z, 12) QKW(c1.w, 14)
        QKW(c2.x, 16) QKW(c2.y, 18) QKW(c2.z, 20) QKW(c2.w, 22)
        QKW(c3.x, 24) QKW(c3.y, 26) QKW(c3.z, 28) QKW(c3.w, 30)
        l[f] = (a0 + a1) * SCALE;
        logit_out[(size_t)(baseB + g * GG + f) * S_LEN + s0 + s] = l[f];
    }
#undef QKW

    // ---- softmax over f, fully thread-local ----
    float tm[16];
    #pragma unroll
    for (int i = 0; i < 16; ++i) tm[i] = fmaxf(l[2 * i], l[2 * i + 1]);
    #pragma unroll
    for (int i = 0; i < 8; ++i) tm[i] = fmaxf(tm[i], tm[i + 8]);
    #pragma unroll
    for (int i = 0; i < 4; ++i) tm[i] = fmaxf(tm[i], tm[i + 4]);
    const float m = fmaxf(fmaxf(tm[0], tm[1]), fmaxf(tm[2], tm[3]));

    float ts4[4] = {0.f, 0.f, 0.f, 0.f};
    #pragma unroll
    for (int f = 0; f < 32; ++f) {
        l[f] = __expf(l[f] - m);
        ts4[f & 3] += l[f];
    }
    const float sum = (ts4[0] + ts4[1]) + (ts4[2] + ts4[3]);
    const float inv = __builtin_amdgcn_rcpf(sum);
    #pragma unroll
    for (int f = 0; f < 32; ++f) {
        l[f] *= inv;
        attn_out[(size_t)(baseB + g * GG + f) * S_LEN + s0 + s] = l[f];
    }

    // ---- PV: x[d] = sum_f a[f] * v[f][d] ----
    float xa[32];
    #pragma unroll
    for (int d = 0; d < 32; ++d) xa[d] = 0.f;
#define PVW(u, d0) { \
        const float vlo_ = __uint_as_float((u) << 16); \
        const float vhi_ = __uint_as_float((u) & 0xffff0000u); \
        xa[d0] = fmaf(av, vlo_, xa[d0]); \
        xa[(d0) + 1] = fmaf(av, vhi_, xa[(d0) + 1]); }
    #pragma unroll
    for (int f = 0; f < 32; ++f) {
        const float av = l[f];
        const uint4 c0 = *reinterpret_cast<const uint4*>(rp0 + 8192 + f * 256);
        const uint4 c1 = *reinterpret_cast<const uint4*>(rp1 + 8192 + f * 256);
        const uint4 c2 = *reinterpret_cast<const uint4*>(rp2 + 8192 + f * 256);
        const uint4 c3 = *reinterpret_cast<const uint4*>(rp3 + 8192 + f * 256);
        PVW(c0.x,  0) PVW(c0.y,  2) PVW(c0.z,  4) PVW(c0.w,  6)
        PVW(c1.x,  8) PVW(c1.y, 10) PVW(c1.z, 12) PVW(c1.w, 14)
        PVW(c2.x, 16) PVW(c2.y, 18) PVW(c2.z, 20) PVW(c2.w, 22)
        PVW(c3.x, 24) PVW(c3.y, 26) PVW(c3.z, 28) PVW(c3.w, 30)
    }
#undef PVW
    #pragma unroll
    for (int d = 0; d < 32; ++d)
        x_out[(size_t)(baseB + g * HH + d) * S_LEN + s0 + s] = xa[d];
}

extern "C" void kernel_launch(void* const* d_in, const int* in_sizes, int n_in,
                              void* d_out, int out_size, void* d_ws, size_t ws_size,
                              hipStream_t stream) {
    const float* q = (const float*)d_in[0];
    const float* k = (const float*)d_in[1];
    const float* v = (const float*)d_in[2];
    float* out = (float*)d_out;
    const int n = in_sizes[0];                  // B*G*H*S = 67108864
    const int B = n / (GG * HH * S_LEN);        // 16
    float* x_out     = out;
    float* attn_out  = out + (size_t)n;
    float* logit_out = out + (size_t)2 * n;
    const int nwg = B * (S_LEN / TS);           // 4096
    tamcad_fused<<<dim3(nwg), dim3(512), 0, stream>>>(q, k, v, x_out, attn_out, logit_out);
}